// Round 2
// baseline (209.983 us; speedup 1.0000x reference)
//
#include <hip/hip_runtime.h>
#include <math.h>

#define ALPHA   0.2f
#define B_DIM   8
#define N_NODES 1024
#define FIN     64
#define T_DIM   8
#define O_DIM   128
#define MAXN    256

// ---------------------------------------------------------------------------
// Kernel 1: Wh[b][n][t][o] = sum_f x[b,n,f,t] * W[f,o]   (fused transpose+GEMM)
// Layout note: Wh stored n-major, t-minor so that one node's data for ALL 8 t
// is one contiguous 4 KB block (k_agg gathers it as a unit).
// Also fused: Wh1[bt][n] = Wh . a1, Wh2[bt][n] = Wh . a2
// Block: 256 threads = (t 0..7) x (oq 0..31). Tile: 8 n-rows. Grid: (N/8, B).
// x staged TRANSPOSED in LDS ([n][t][f], f contiguous) so the k-loop reads
// x fragments with ds_read_b128 (192 LDS instrs/thread vs 576 scalar).
// ---------------------------------------------------------------------------
__global__ __launch_bounds__(256) void k_wh(const float* __restrict__ x,
                                            const float* __restrict__ W,
                                            const float* __restrict__ a,
                                            float* __restrict__ Wh,
                                            float* __restrict__ Wh1,
                                            float* __restrict__ Wh2) {
    __shared__ float  xs[8 * 8 * 64];   // [n][t][f], 16 KB
    __shared__ float4 Ws4[64 * 32];     // [k][oq] as float4, 32 KB

    const int tid = threadIdx.x;
    const int n0  = blockIdx.x * 8;
    const int b   = blockIdx.y;

    // stage x tile transposed: in-memory float4 = x[b, n, f, 4tq..4tq+3]
    const float4* xg4 = (const float4*)(x + (size_t)(b * N_NODES + n0) * (FIN * T_DIM));
    #pragma unroll
    for (int i = 0; i < 4; ++i) {
        int    idx = tid + i * 256;        // 0..1023
        float4 v   = xg4[idx];
        int n   = idx >> 7;                // idx / 128
        int rem = idx & 127;
        int f   = rem >> 1;
        int tq  = rem & 1;                 // t = tq*4 + j
        float* dst = &xs[((n << 3) + (tq << 2)) * 64 + f];
        dst[0 * 64] = v.x; dst[1 * 64] = v.y; dst[2 * 64] = v.z; dst[3 * 64] = v.w;
    }

    // stage W: 64x128 = 2048 float4, coalesced
    const float4* Wg4 = (const float4*)W;
    #pragma unroll
    for (int i = 0; i < 8; ++i) Ws4[tid + i * 256] = Wg4[tid + i * 256];
    __syncthreads();

    const int oq = tid & 31;   // o-quad: o = oq*4 .. oq*4+3
    const int t  = tid >> 5;   // 0..7

    float4 acc[8];
    #pragma unroll
    for (int n = 0; n < 8; ++n) { acc[n].x = 0.f; acc[n].y = 0.f; acc[n].z = 0.f; acc[n].w = 0.f; }

    #pragma unroll 4
    for (int k = 0; k < FIN; k += 4) {
        float4 w0 = Ws4[(k + 0) * 32 + oq];
        float4 w1 = Ws4[(k + 1) * 32 + oq];
        float4 w2 = Ws4[(k + 2) * 32 + oq];
        float4 w3 = Ws4[(k + 3) * 32 + oq];
        #pragma unroll
        for (int n = 0; n < 8; ++n) {
            float4 xq = *(const float4*)&xs[((n << 3) + t) * 64 + k];  // b128, 2-way bcast
            acc[n].x = fmaf(xq.w, w3.x, fmaf(xq.z, w2.x, fmaf(xq.y, w1.x, fmaf(xq.x, w0.x, acc[n].x))));
            acc[n].y = fmaf(xq.w, w3.y, fmaf(xq.z, w2.y, fmaf(xq.y, w1.y, fmaf(xq.x, w0.y, acc[n].y))));
            acc[n].z = fmaf(xq.w, w3.z, fmaf(xq.z, w2.z, fmaf(xq.y, w1.z, fmaf(xq.x, w0.z, acc[n].z))));
            acc[n].w = fmaf(xq.w, w3.w, fmaf(xq.z, w2.w, fmaf(xq.y, w1.w, fmaf(xq.x, w0.w, acc[n].w))));
        }
    }

    // store Wh[b][n][t][o] (coalesced float4; wave covers 2 contiguous 512B t-slices)
    float4* Whg4 = (float4*)Wh;
    #pragma unroll
    for (int n = 0; n < 8; ++n) {
        Whg4[((size_t)(b * N_NODES + n0 + n) * T_DIM + t) * 32 + oq] = acc[n];
    }

    // fused Wh1/Wh2: dot over o, reduce across the 32 oq lanes (same half-wave)
    const int bt = b * T_DIM + t;
    const float4* a4 = (const float4*)a;
    const float4 a1v = a4[oq];        // a[:128]
    const float4 a2v = a4[32 + oq];   // a[128:256]
    #pragma unroll
    for (int n = 0; n < 8; ++n) {
        float s1 = acc[n].x * a1v.x + acc[n].y * a1v.y + acc[n].z * a1v.z + acc[n].w * a1v.w;
        float s2 = acc[n].x * a2v.x + acc[n].y * a2v.y + acc[n].z * a2v.z + acc[n].w * a2v.w;
        #pragma unroll
        for (int off = 1; off < 32; off <<= 1) {
            s1 += __shfl_xor(s1, off);
            s2 += __shfl_xor(s2, off);
        }
        if (oq == 0) {
            Wh1[(size_t)bt * N_NODES + n0 + n] = s1;
            Wh2[(size_t)bt * N_NODES + n0 + n] = s2;
        }
    }
}

// ---------------------------------------------------------------------------
// Kernel 2: build neighbor lists from adj (same for all b,t).
// ---------------------------------------------------------------------------
__global__ __launch_bounds__(256) void k_csr(const float* __restrict__ adj,
                                             int* __restrict__ cnt,
                                             int* __restrict__ nbr) {
    __shared__ int scnt;
    const int i = blockIdx.x;
    if (threadIdx.x == 0) scnt = 0;
    __syncthreads();
    for (int j = threadIdx.x; j < N_NODES; j += 256) {
        if (adj[(size_t)i * N_NODES + j] > 0.0f) {
            int pos = atomicAdd(&scnt, 1);
            if (pos < MAXN) nbr[i * MAXN + pos] = j;
        }
    }
    __syncthreads();
    if (threadIdx.x == 0) cnt[i] = min(scnt, MAXN);
}

// ---------------------------------------------------------------------------
// Kernel 3: sparse softmax + aggregation + ELU + transposed store.
// 1D grid, b = blockIdx & 7: round-robin block->XCD dispatch pins each 4 MB
// Wh[b] plane to one XCD's 4 MB L2 (gathers become L2 hits).
// Block: 512 threads = 8 waves; wave w = t. j-rows are 4 KB contiguous
// (Wh[b][j][t][o]) shared across the 8 waves; each wave reads its 512 B
// t-slice as one dwordx2 per lane. Phase B unrolled x4 for MLP.
// ---------------------------------------------------------------------------
__global__ __launch_bounds__(512) void k_agg(const float* __restrict__ Wh,
                                             const float* __restrict__ Wh1,
                                             const float* __restrict__ Wh2,
                                             const int* __restrict__ cnt,
                                             const int* __restrict__ nbr,
                                             float* __restrict__ out) {
    __shared__ int   j_lds[MAXN];                 // 1 KB
    __shared__ float p_lds[T_DIM * MAXN];         // 8 KB
    __shared__ float out_lds[O_DIM * 9];          // 4.5 KB, pad 9 -> conflict-free

    const int tid = threadIdx.x;
    const int w   = tid >> 6;    // wave id = t
    const int l   = tid & 63;    // lane
    const int b   = blockIdx.x & 7;     // XCD-pinned batch
    const int i   = blockIdx.x >> 3;

    const int c = cnt[i];
    for (int jj = tid; jj < c; jj += 512) j_lds[jj] = nbr[i * MAXN + jj];
    __syncthreads();

    const int   t  = w;
    const int   bt = b * T_DIM + t;
    const float h1 = Wh1[(size_t)bt * N_NODES + i];
    const float* wh2row = Wh2 + (size_t)bt * N_NODES;

    // phase A: leaky-relu scores, running max (store e in p_lds)
    float m = -INFINITY;
    for (int jj = l; jj < c; jj += 64) {
        int   j = j_lds[jj];
        float e = h1 + wh2row[j];
        e = e > 0.0f ? e : ALPHA * e;
        p_lds[w * MAXN + jj] = e;
        m = fmaxf(m, e);
    }
    #pragma unroll
    for (int off = 1; off < 64; off <<= 1) m = fmaxf(m, __shfl_xor(m, off));

    // exp + sum (same-lane RAW on p_lds)
    float s = 0.0f;
    for (int jj = l; jj < c; jj += 64) {
        float p = __expf(p_lds[w * MAXN + jj] - m);
        p_lds[w * MAXN + jj] = p;
        s += p;
    }
    #pragma unroll
    for (int off = 1; off < 64; off <<= 1) s += __shfl_xor(s, off);
    const float linv = 1.0f / s;

    __syncthreads();   // cross-lane p_lds visibility (uniform trip counts: safe)

    // phase B: weighted gather. lane l owns channels 2l, 2l+1 (one dwordx2/row).
    const float* base_bt = Wh + ((size_t)b * N_NODES * T_DIM + t) * O_DIM + 2 * l;
    const float* prow    = p_lds + w * MAXN;
    float2 acc; acc.x = 0.f; acc.y = 0.f;

    int jj = 0;
    for (; jj + 3 < c; jj += 4) {
        int j0 = j_lds[jj], j1 = j_lds[jj + 1], j2 = j_lds[jj + 2], j3 = j_lds[jj + 3];
        float2 v0 = *(const float2*)(base_bt + (size_t)j0 * (T_DIM * O_DIM));
        float2 v1 = *(const float2*)(base_bt + (size_t)j1 * (T_DIM * O_DIM));
        float2 v2 = *(const float2*)(base_bt + (size_t)j2 * (T_DIM * O_DIM));
        float2 v3 = *(const float2*)(base_bt + (size_t)j3 * (T_DIM * O_DIM));
        float p0 = prow[jj], p1 = prow[jj + 1], p2 = prow[jj + 2], p3 = prow[jj + 3];
        acc.x = fmaf(p0, v0.x, acc.x); acc.y = fmaf(p0, v0.y, acc.y);
        acc.x = fmaf(p1, v1.x, acc.x); acc.y = fmaf(p1, v1.y, acc.y);
        acc.x = fmaf(p2, v2.x, acc.x); acc.y = fmaf(p2, v2.y, acc.y);
        acc.x = fmaf(p3, v3.x, acc.x); acc.y = fmaf(p3, v3.y, acc.y);
    }
    for (; jj < c; ++jj) {
        int    j = j_lds[jj];
        float2 v = *(const float2*)(base_bt + (size_t)j * (T_DIM * O_DIM));
        float  p = prow[jj];
        acc.x = fmaf(p, v.x, acc.x); acc.y = fmaf(p, v.y, acc.y);
    }

    float v0 = acc.x * linv, v1 = acc.y * linv;
    v0 = v0 > 0.0f ? v0 : __expf(v0) - 1.0f;     // ELU
    v1 = v1 > 0.0f ? v1 : __expf(v1) - 1.0f;
    out_lds[(2 * l)     * 9 + t] = v0;
    out_lds[(2 * l + 1) * 9 + t] = v1;
    __syncthreads();

    // out[b,i,o,t]: 1024 contiguous floats per (b,i), coalesced
    float* orow = out + ((size_t)b * N_NODES + i) * (O_DIM * T_DIM);
    for (int idx = tid; idx < O_DIM * T_DIM; idx += 512) {
        orow[idx] = out_lds[(idx >> 3) * 9 + (idx & 7)];
    }
}

// ---------------------------------------------------------------------------
extern "C" void kernel_launch(void* const* d_in, const int* in_sizes, int n_in,
                              void* d_out, int out_size, void* d_ws, size_t ws_size,
                              hipStream_t stream) {
    const float* x   = (const float*)d_in[0];   // (8,1024,64,8)
    const float* adj = (const float*)d_in[1];   // (1024,1024)
    const float* W   = (const float*)d_in[2];   // (64,128)
    const float* a   = (const float*)d_in[3];   // (256,1)
    float* out = (float*)d_out;                 // (8,1024,128,8)

    // workspace carve-up
    float* Wh  = (float*)d_ws;                         // 8*1024*8*128 = 8388608 f
    float* Wh1 = Wh + (size_t)8388608;                 // 65536 f
    float* Wh2 = Wh1 + 65536;                          // 65536 f
    int*   cnt = (int*)(Wh2 + 65536);                  // 1024 i
    int*   nbr = cnt + 1024;                           // 1024*256 i

    k_wh <<<dim3(N_NODES / 8, B_DIM), 256, 0, stream>>>(x, W, a, Wh, Wh1, Wh2);
    k_csr<<<N_NODES, 256, 0, stream>>>(adj, cnt, nbr);
    k_agg<<<N_NODES * B_DIM, 512, 0, stream>>>(Wh, Wh1, Wh2, cnt, nbr, out);
}

// Round 4
// 151.327 us; speedup vs baseline: 1.3876x; 1.3876x over previous
//
#include <hip/hip_runtime.h>
#include <math.h>
#include <stdint.h>

#define ALPHA 0.2f

typedef __attribute__((ext_vector_type(8))) short bf16x8;
typedef __attribute__((ext_vector_type(4))) float f32x4;

// ---------------------------------------------------------------------------
// Kernel 1: k_wh — Wh = (x^T)W fused transpose-GEMM, emitting Wh directly in
// MFMA B-fragment layout (bf16), plus fp32 Wh1/Wh2 score vectors.
//
// Grid 256 = (8 b x 32 j-tiles of 32). Block 512 = 8 waves, wave = t.
// Lane (q = lane>>4, om = lane&15) computes acc[jj][nt] for
//   j = jt*32 + q*8 + jj   (jj 0..7)
//   o = nt*16 + om         (nt 0..7)
// which IS the element set of B-frags (jt, nt) for mfma_f32_16x16x32_bf16
// (B[k = (lane>>4)*8 + jj][n = lane&15]) -> one uint4 store per nt.
//
// x staged in LDS as [jl][t][k ^ jquad-swizzle] (b128 reads conflict-free);
// W staged transposed as Wv[o][k] (pad 68 -> 2-way bcast+2-way bank = free).
// LDS 98 KB static (compiles on gfx950 -> within target limit), 1 block/CU.
// ---------------------------------------------------------------------------
__global__ __launch_bounds__(512) void k_wh(const float* __restrict__ x,
                                            const float* __restrict__ W,
                                            const float* __restrict__ a,
                                            uint4* __restrict__ Whf,
                                            float* __restrict__ Wh1,
                                            float* __restrict__ Wh2) {
    __shared__ float xs[32 * 512];        // [jl][t][k ^ swz], 64 KB
    __shared__ float Wv[8 * 16 * 68];     // [nt][om][k], pad 68, 34.8 KB

    const int tid = threadIdx.x;
    const int b   = blockIdx.x & 7;
    const int jt  = blockIdx.x >> 3;      // 0..31

    // stage x: 32 rows x 512 floats = 4096 float4 (8 iters x 512 threads)
    const float4* xg4 = (const float4*)(x + ((size_t)(b * 1024 + jt * 32)) * 512);
    #pragma unroll
    for (int i = 0; i < 8; ++i) {
        int    idx = tid + i * 512;       // float4 index 0..4095
        float4 v   = xg4[idx];
        int jl  = idx >> 7;               // 0..31 (128 float4 per row)
        int rem = idx & 127;
        int f   = rem >> 1;               // 0..63
        int tq  = rem & 1;                // t = tq*4 + c
        int kk  = f ^ ((jl >> 3) << 2);   // k-swizzle by j-quad
        float* dst = &xs[jl * 512 + (tq * 4) * 64 + kk];
        dst[0]   = v.x;
        dst[64]  = v.y;
        dst[128] = v.z;
        dst[192] = v.w;
    }
    // stage Wv[o][k] = W[k][o]  (2048 float4)
    const float4* Wg4 = (const float4*)W;
    #pragma unroll
    for (int i = 0; i < 4; ++i) {
        int    idx = tid + i * 512;       // 0..2047
        float4 v   = Wg4[idx];
        int k  = idx >> 5;
        int o0 = (idx & 31) * 4;
        #pragma unroll
        for (int c = 0; c < 4; ++c) {
            int o = o0 + c;
            Wv[o * 68 + k] = (&v.x)[c];
        }
    }
    __syncthreads();

    const int w  = tid >> 6;              // wave = t (0..7)
    const int l  = tid & 63;
    const int q  = l >> 4;                // k-quad
    const int om = l & 15;                // o within 16
    const int t  = w;

    float acc[8][8];                      // [jj][nt]
    #pragma unroll
    for (int jj = 0; jj < 8; ++jj)
        #pragma unroll
        for (int nt = 0; nt < 8; ++nt) acc[jj][nt] = 0.f;

    for (int kc = 0; kc < 64; kc += 4) {
        float4 xv[8], wv[8];
        const int kx = kc ^ (q << 2);
        #pragma unroll
        for (int jj = 0; jj < 8; ++jj)
            xv[jj] = *(const float4*)&xs[(q * 8 + jj) * 512 + t * 64 + kx];
        #pragma unroll
        for (int nt = 0; nt < 8; ++nt)
            wv[nt] = *(const float4*)&Wv[(nt * 16 + om) * 68 + kc];
        #pragma unroll
        for (int jj = 0; jj < 8; ++jj) {
            #pragma unroll
            for (int nt = 0; nt < 8; ++nt) {
                float s = acc[jj][nt];
                s = fmaf(xv[jj].x, wv[nt].x, s);
                s = fmaf(xv[jj].y, wv[nt].y, s);
                s = fmaf(xv[jj].z, wv[nt].z, s);
                s = fmaf(xv[jj].w, wv[nt].w, s);
                acc[jj][nt] = s;
            }
        }
    }

    const int bt = b * 8 + t;

    // Wh1/Wh2: dot with a1/a2 over o, reduce across the 16 om-lanes
    float a1v[8], a2v[8];
    #pragma unroll
    for (int nt = 0; nt < 8; ++nt) {
        a1v[nt] = a[nt * 16 + om];
        a2v[nt] = a[128 + nt * 16 + om];
    }
    #pragma unroll
    for (int jj = 0; jj < 8; ++jj) {
        float s1 = 0.f, s2 = 0.f;
        #pragma unroll
        for (int nt = 0; nt < 8; ++nt) {
            s1 = fmaf(acc[jj][nt], a1v[nt], s1);
            s2 = fmaf(acc[jj][nt], a2v[nt], s2);
        }
        #pragma unroll
        for (int off = 1; off < 16; off <<= 1) {
            s1 += __shfl_xor(s1, off);
            s2 += __shfl_xor(s2, off);
        }
        if (om == 0) {
            int j = jt * 32 + q * 8 + jj;
            Wh1[bt * 1024 + j] = s1;
            Wh2[bt * 1024 + j] = s2;
        }
    }

    // frag pack + store (bf16 round-half-up on magnitude)
    #pragma unroll
    for (int nt = 0; nt < 8; ++nt) {
        uint32_t u[4];
        #pragma unroll
        for (int pr = 0; pr < 4; ++pr) {
            uint32_t lo = (__float_as_uint(acc[2 * pr][nt]) + 0x8000u) >> 16;
            uint32_t hi = (__float_as_uint(acc[2 * pr + 1][nt]) + 0x8000u) & 0xFFFF0000u;
            u[pr] = lo | hi;
        }
        uint4 st; st.x = u[0]; st.y = u[1]; st.z = u[2]; st.w = u[3];
        Whf[((size_t)(bt * 32 + jt) * 8 + nt) * 64 + l] = st;
    }
}

// ---------------------------------------------------------------------------
// Kernel 2: adj -> byte bitmask adjb[i][j/8] (128 KB)
// ---------------------------------------------------------------------------
__global__ __launch_bounds__(256) void k_adjb(const float* __restrict__ adj,
                                              unsigned char* __restrict__ adjb) {
    int idx = blockIdx.x * 256 + threadIdx.x;       // 0..131071
    const float4* a4 = (const float4*)adj + idx * 2;
    float4 v0 = a4[0], v1 = a4[1];
    unsigned int by = 0;
    by |= (v0.x > 0.f) ? 1u : 0u;
    by |= (v0.y > 0.f) ? 2u : 0u;
    by |= (v0.z > 0.f) ? 4u : 0u;
    by |= (v0.w > 0.f) ? 8u : 0u;
    by |= (v1.x > 0.f) ? 16u : 0u;
    by |= (v1.y > 0.f) ? 32u : 0u;
    by |= (v1.z > 0.f) ? 64u : 0u;
    by |= (v1.w > 0.f) ? 128u : 0u;
    adjb[idx] = (unsigned char)by;
}

// ---------------------------------------------------------------------------
// Kernel 3: k_agg — dense flash aggregation with rank-1 scores + MFMA PV.
// Grid 512: blockIdx = ((itile*8 + t)*8 + b)  ->  XCD = b (L2 pins the 8
// Whf planes of batch b, 2 MB), and the 8 t-blocks of one (b,itile) are
// dispatch-adjacent so their partial out-lines merge in the same L2.
// Block 256 = 4 waves; wave w owns i-rows [i0+w*32, +32) as 2 ms 16-tiles.
// Per 32-j step: build P A-frag in-register (e = Wh1_i + Wh2_j, lrelu, mask
// bit, exp with safe max m' = lrelu(Wh1_i + max_j Wh2_j) — monotone lrelu
// makes m' an upper bound; constant factor cancels in normalization; l is
// accumulated from the bf16-ROUNDED p so it matches the MFMA sum exactly),
// then 8 nt x 2 ms mfma_f32_16x16x32_bf16 against pre-packed B-frags.
// ---------------------------------------------------------------------------
__global__ __launch_bounds__(256) void k_agg(const uint4* __restrict__ Whf,
                                             const float* __restrict__ Wh1,
                                             const float* __restrict__ Wh2,
                                             const unsigned char* __restrict__ adjb,
                                             float* __restrict__ out) {
    __shared__ float        wh2s[1024];           // 4 KB
    __shared__ unsigned int adjs_u[128 * 33];     // 16.5 KB, row pad 132 B
    __shared__ float        wh1s[128];
    __shared__ float        lls[128];
    __shared__ float        m2s[4];

    const int tid   = threadIdx.x;
    const int b     = blockIdx.x & 7;
    const int t     = (blockIdx.x >> 3) & 7;
    const int itile = blockIdx.x >> 6;            // 0..7
    const int bt    = b * 8 + t;
    const int i0    = itile * 128;

    // stage Wh2 plane row, Wh1 slice, adj bitmask slice (all coalesced)
    const float* wh2g = Wh2 + bt * 1024;
    for (int i = tid; i < 1024; i += 256) wh2s[i] = wh2g[i];
    if (tid < 128) wh1s[tid] = Wh1[bt * 1024 + i0 + tid];
    const unsigned int* adjg_u = (const unsigned int*)(adjb + i0 * 128);
    for (int idx = tid; idx < 4096; idx += 256)
        adjs_u[(idx >> 5) * 33 + (idx & 31)] = adjg_u[idx];
    __syncthreads();

    const int w = tid >> 6;                       // wave 0..3
    const int l = tid & 63;
    const int q = l >> 4;                         // k-quad
    const int m = l & 15;

    // block max of Wh2 (safe softmax max ingredient)
    float mx = fmaxf(fmaxf(wh2s[w * 256 + l], wh2s[w * 256 + 64 + l]),
                     fmaxf(wh2s[w * 256 + 128 + l], wh2s[w * 256 + 192 + l]));
    #pragma unroll
    for (int off = 1; off < 64; off <<= 1) mx = fmaxf(mx, __shfl_xor(mx, off));
    if (l == 0) m2s[w] = mx;
    __syncthreads();
    const float M2 = fmaxf(fmaxf(m2s[0], m2s[1]), fmaxf(m2s[2], m2s[3]));

    float wh1v[2], mc[2];
    #pragma unroll
    for (int ms = 0; ms < 2; ++ms) {
        float h1 = wh1s[w * 32 + ms * 16 + m];
        float e  = h1 + M2;
        wh1v[ms] = h1;
        mc[ms]   = fmaxf(e, ALPHA * e);           // m' >= every unmasked lrelu(e)
    }

    f32x4 acc[2][8];
    #pragma unroll
    for (int ms = 0; ms < 2; ++ms)
        #pragma unroll
        for (int nt = 0; nt < 8; ++nt) { acc[ms][nt] = (f32x4){0.f, 0.f, 0.f, 0.f}; }
    float lacc[2] = {0.f, 0.f};

    const uint4*         bfg  = Whf + (size_t)bt * 32 * 8 * 64 + l;
    const unsigned char* adjs = (const unsigned char*)adjs_u;
    const int            arow = (w * 32 + m) * 132;

    for (int s = 0; s < 32; ++s) {
        union { float4 f4[2]; float f[8]; } w2;
        w2.f4[0] = *(const float4*)&wh2s[s * 32 + q * 8];
        w2.f4[1] = *(const float4*)&wh2s[s * 32 + q * 8 + 4];
        unsigned int byv[2];
        byv[0] = adjs[arow + s * 4 + q];
        byv[1] = adjs[arow + 16 * 132 + s * 4 + q];

        bf16x8 afr[2];
        #pragma unroll
        for (int ms = 0; ms < 2; ++ms) {
            const float h1 = wh1v[ms], mp = mc[ms];
            const unsigned int by = byv[ms];
            uint32_t ub[8];
            float    ls = 0.f;
            #pragma unroll
            for (int jj = 0; jj < 8; ++jj) {
                float e   = h1 + w2.f[jj];
                float lr  = fmaxf(e, ALPHA * e);
                float arg = ((by >> jj) & 1u) ? (lr - mp) : -1e30f;
                float p   = __expf(arg);               // in (0,1], 0 if masked
                uint32_t r = (__float_as_uint(p) + 0x8000u) >> 16;  // bf16 bits
                ub[jj] = r;
                ls += __uint_as_float(r << 16);        // l from rounded p
            }
            union { uint32_t u[4]; bf16x8 v; } pk;
            #pragma unroll
            for (int pr = 0; pr < 4; ++pr)
                pk.u[pr] = ub[2 * pr] | (ub[2 * pr + 1] << 16);
            afr[ms] = pk.v;
            lacc[ms] += ls;
        }

        const uint4* bp = bfg + (size_t)s * 8 * 64;
        #pragma unroll
        for (int nt = 0; nt < 8; ++nt) {
            union { uint4 u; bf16x8 v; } br;
            br.u = bp[nt * 64];
            acc[0][nt] = __builtin_amdgcn_mfma_f32_16x16x32_bf16(afr[0], br.v, acc[0][nt], 0, 0, 0);
            acc[1][nt] = __builtin_amdgcn_mfma_f32_16x16x32_bf16(afr[1], br.v, acc[1][nt], 0, 0, 0);
        }
    }

    // combine l across the 4 k-quads (lanes sharing m)
    #pragma unroll
    for (int ms = 0; ms < 2; ++ms) {
        lacc[ms] += __shfl_xor(lacc[ms], 16);
        lacc[ms] += __shfl_xor(lacc[ms], 32);
    }
    if (q == 0) {
        lls[w * 32 + m]      = lacc[0];
        lls[w * 32 + 16 + m] = lacc[1];
    }
    __syncthreads();

    // epilogue: normalize, ELU, scatter-store (lines merge in-XCD L2)
    float* og = out + ((size_t)(b * 1024 + i0 + w * 32)) * 1024 + t;
    #pragma unroll
    for (int ms = 0; ms < 2; ++ms) {
        #pragma unroll
        for (int reg = 0; reg < 4; ++reg) {
            int   row  = ms * 16 + q * 4 + reg;
            float linv = 1.0f / lls[w * 32 + row];
            #pragma unroll
            for (int nt = 0; nt < 8; ++nt) {
                float v = acc[ms][nt][reg] * linv;
                v = v > 0.f ? v : __expf(v) - 1.f;
                og[(size_t)row * 1024 + (nt * 16 + m) * 8] = v;
            }
        }
    }
}

// ---------------------------------------------------------------------------
extern "C" void kernel_launch(void* const* d_in, const int* in_sizes, int n_in,
                              void* d_out, int out_size, void* d_ws, size_t ws_size,
                              hipStream_t stream) {
    const float* x   = (const float*)d_in[0];   // (8,1024,64,8)
    const float* adj = (const float*)d_in[1];   // (1024,1024)
    const float* W   = (const float*)d_in[2];   // (64,128)
    const float* a   = (const float*)d_in[3];   // (256,1)
    float* out = (float*)d_out;                 // (8,1024,128,8)

    uint4*         Whf  = (uint4*)d_ws;                        // 1048576 uint4 = 16 MB
    float*         Wh1  = (float*)(Whf + 1048576);             // 65536 f
    float*         Wh2  = Wh1 + 65536;                         // 65536 f
    unsigned char* adjb = (unsigned char*)(Wh2 + 65536);       // 131072 B

    k_wh  <<<256, 512, 0, stream>>>(x, W, a, Whf, Wh1, Wh2);
    k_adjb<<<512, 256, 0, stream>>>(adj, adjb);
    k_agg <<<512, 256, 0, stream>>>(Whf, Wh1, Wh2, adjb, out);
}